// Round 8
// baseline (41.356 us; speedup 1.0000x reference)
//
#include <hip/hip_runtime.h>

namespace {

constexpr int kT   = 8;    // timesteps
constexpr int kB   = 256;  // batch
constexpr int kNQ  = 8;    // qubits per circuit
constexpr int kNB  = 8;    // blocks
constexpr int kD   = 64;   // features
constexpr int kNL  = 2;    // quantum layers
constexpr int kCirc = kT * kNB;        // 64 circuits per layer
constexpr int kGates = 2 * kNQ;        // 16 gate slots per circuit
constexpr int kGateF = 8;

// ---------------- Rot-gate precompute ----------------
// slots (d=0,w=0..7) and (d=1,w=0..5): full 2x2 complex gate (8 floats)
// slots (d=1,w=6..7): Hermitian h = g^dag Z g stored as (a, Re b, Im b, 0...)
__global__ void precompute_gates(const float* __restrict__ theta, float* __restrict__ gt) {
    int i = blockIdx.x * blockDim.x + threadIdx.x;
    if (i >= kNL * kCirc * kGates) return;
    int g = i & 15;
    int c = (i >> 4) & 63;
    int l = i >> 10;
    int t = c >> 3, u = c & 7;
    int d = g >> 3, w = g & 7;
    const float* th = theta + ((((t * kNL + l) * kNB + u) * 2 + d) * kNQ + w) * 3;
    float phi = th[0], tht = th[1], omg = th[2];
    float st, ct, sp, cp, sm, cm;
    __sincosf(0.5f * tht, &st, &ct);
    __sincosf(0.5f * (phi + omg), &sp, &cp);
    __sincosf(0.5f * (phi - omg), &sm, &cm);
    const float u00r =  ct * cp, u00i = -ct * sp;
    const float u01r = -st * cm, u01i = -st * sm;
    const float u10r =  st * cm, u10i = -st * sm;
    const float u11r =  ct * cp, u11i =  ct * sp;
    float* o = gt + i * kGateF;
    if (d == 1 && w >= 6) {
        // h = g^dag Z g: h00 = |u00|^2-|u10|^2, h01 = conj(u00)u01 - conj(u10)u11
        o[0] = (u00r * u00r + u00i * u00i) - (u10r * u10r + u10i * u10i);
        o[1] = (u00r * u01r + u00i * u01i) - (u10r * u11r + u10i * u11i);
        o[2] = (u00r * u01i - u00i * u01r) - (u10r * u11i - u10i * u11r);
        o[3] = 0.0f; o[4] = 0.0f; o[5] = 0.0f; o[6] = 0.0f; o[7] = 0.0f;
    } else {
        o[0] = u00r;  o[1] = u00i;
        o[2] = u01r;  o[3] = u01i;
        o[4] = u10r;  o[5] = u10i;
        o[6] = u11r;  o[7] = u11i;
    }
}

// ---------------- shuffle backends ----------------
template <int CTRL>
__device__ __forceinline__ float f_dpp(float x) {
    return __builtin_bit_cast(float, __builtin_amdgcn_update_dpp(
        0, __builtin_bit_cast(int, x), CTRL, 0xF, 0xF, true));
}
constexpr int kDppXor1 = 0xB1;   // quad_perm [1,0,3,2]  = lane^1
constexpr int kDppXor2 = 0x4E;   // quad_perm [2,3,0,1]  = lane^2
constexpr int kDppXor8 = 0x128;  // row_ror:8 (16-lane row) = lane^8  [validated r7]

// partner fetch at lane distance 1<<MODE: 0,1,3 via DPP (VALU); 2,4,5 via shfl (DS)
template <int MODE>
__device__ __forceinline__ float lane_partner(float x) {
    if constexpr (MODE == 0) return f_dpp<kDppXor1>(x);
    else if constexpr (MODE == 1) return f_dpp<kDppXor2>(x);
    else if constexpr (MODE == 3) return f_dpp<kDppXor8>(x);
    else if constexpr (MODE == 2) return __shfl_xor(x, 4, 64);
    else if constexpr (MODE == 4) return __shfl_xor(x, 16, 64);
    else return __shfl_xor(x, 32, 64);
}

__device__ __forceinline__ float signflip(float v, unsigned sgn) {
    return __builtin_bit_cast(float, __builtin_bit_cast(unsigned, v) ^ sgn);
}

// ---------------- gate helper (1 sample/wave, 4 amps/lane) ----------------
// amp index k = (lane<<2)|reg; wire w -> index bit 7-w.
// wires 0..5 -> lane bits 5..0; wires 6,7 -> reg bits 1,0.
template <int MODE>
__device__ __forceinline__ void gate_direct(float (&re)[4], float (&im)[4], int bit,
                                            const float* __restrict__ gp) {
    const float aR = bit ? gp[6] : gp[0];
    const float aI = bit ? gp[7] : gp[1];
    const float bR = bit ? gp[4] : gp[2];
    const float bI = bit ? gp[5] : gp[3];
#pragma unroll
    for (int r = 0; r < 4; ++r) {
        const float pre = lane_partner<MODE>(re[r]);
        const float pim = lane_partner<MODE>(im[r]);
        const float mre = re[r], mim = im[r];
        re[r] = aR * mre - aI * mim + bR * pre - bI * pim;
        im[r] = aR * mim + aI * mre + bR * pim + bI * pre;
    }
}

// ---------------- one circuit sim: 1 sample, 3 Walsh streams out ----------------
// State after AngleEmbedding + depth-0 Rot + CNOT-ring1 built directly as a permuted
// spinor product; depth-1 Rot gates on lane-bit wires applied; reg-bit wires (6,7)
// folded as Hermitian quadratic forms (h = g^dag Z g); CNOT-ring2 folded into the
// Walsh parities of the reduction.
__device__ __forceinline__ void sim1(const float (&ang)[8],
                                     const float* __restrict__ g0,
                                     const float* __restrict__ g1,
                                     int lane, const unsigned (&sg)[6],
                                     float& WPo, float& WR1o, float& WR0o) {
    const int l0 = lane & 1,        l1 = (lane >> 1) & 1, l2 = (lane >> 2) & 1;
    const int l3 = (lane >> 3) & 1, l4 = (lane >> 4) & 1, l5 = (lane >> 5) & 1;

    float re[4], im[4];
    {
        // per-wire spinor after RY(ang) then d0 Rot
        float spr[8][2], spi[8][2];
#pragma unroll
        for (int w = 0; w < 8; ++w) {
            float sn, cs;
            __sincosf(0.5f * ang[w], &sn, &cs);
            const float* gp = g0 + w * kGateF;
            spr[w][0] = gp[0] * cs + gp[2] * sn;
            spi[w][0] = gp[1] * cs + gp[3] * sn;
            spr[w][1] = gp[4] * cs + gp[6] * sn;
            spi[w][1] = gp[5] * cs + gp[7] * sn;
        }
        // ring1 inverse bit map (x = pre-ring1 wire bits; (lane,reg) = post-ring1):
        //  x0=l5^r0  x1=l5^l4^r0  x2=l4^l3  x3=l3^l2  x4=l2^l1  x5=l1^l0
        //  x6=l0^r1  x7=r1^r0
        const int x2 = l4 ^ l3, x3 = l3 ^ l2, x4 = l2 ^ l1, x5 = l1 ^ l0;
        float t1r, t1i, t2r, t2i;
        {
            const float ar = x2 ? spr[2][1] : spr[2][0], ai = x2 ? spi[2][1] : spi[2][0];
            const float br = x3 ? spr[3][1] : spr[3][0], bi = x3 ? spi[3][1] : spi[3][0];
            t1r = ar * br - ai * bi; t1i = ar * bi + ai * br;
        }
        {
            const float ar = x4 ? spr[4][1] : spr[4][0], ai = x4 ? spi[4][1] : spi[4][0];
            const float br = x5 ? spr[5][1] : spr[5][0], bi = x5 ? spi[5][1] : spi[5][0];
            t2r = ar * br - ai * bi; t2i = ar * bi + ai * br;
        }
        const float Lr = t1r * t2r - t1i * t2i, Li = t1r * t2i + t1i * t2r;
        // Q(r0) = s0[l5^r0] * s1[l5^l4^r0]
        const int xa = l5, xb = l5 ^ l4;
        const float a0r = xa ? spr[0][1] : spr[0][0], a0i = xa ? spi[0][1] : spi[0][0];
        const float a1r = xa ? spr[0][0] : spr[0][1], a1i = xa ? spi[0][0] : spi[0][1];
        const float b0r = xb ? spr[1][1] : spr[1][0], b0i = xb ? spi[1][1] : spi[1][0];
        const float b1r = xb ? spr[1][0] : spr[1][1], b1i = xb ? spi[1][0] : spi[1][1];
        const float Q0r = a0r * b0r - a0i * b0i, Q0i = a0r * b0i + a0i * b0r;
        const float Q1r = a1r * b1r - a1i * b1i, Q1i = a1r * b1i + a1i * b1r;
        // R(r1) = s6[l0^r1]; S(r0,r1) = s7[r1^r0]
        const float R0r = l0 ? spr[6][1] : spr[6][0], R0i = l0 ? spi[6][1] : spi[6][0];
        const float R1r = l0 ? spr[6][0] : spr[6][1], R1i = l0 ? spi[6][0] : spi[6][1];
        const float S0r = spr[7][0], S0i = spi[7][0];
        const float S1r = spr[7][1], S1i = spi[7][1];
        float RSr[4], RSi[4];
        RSr[0] = R0r * S0r - R0i * S0i; RSi[0] = R0r * S0i + R0i * S0r;  // r=0
        RSr[1] = R0r * S1r - R0i * S1i; RSi[1] = R0r * S1i + R0i * S1r;  // r=1
        RSr[2] = R1r * S1r - R1i * S1i; RSi[2] = R1r * S1i + R1i * S1r;  // r=2
        RSr[3] = R1r * S0r - R1i * S0i; RSi[3] = R1r * S0i + R1i * S0r;  // r=3
        const float LQ0r = Lr * Q0r - Li * Q0i, LQ0i = Lr * Q0i + Li * Q0r;
        const float LQ1r = Lr * Q1r - Li * Q1i, LQ1i = Lr * Q1i + Li * Q1r;
        re[0] = LQ0r * RSr[0] - LQ0i * RSi[0]; im[0] = LQ0r * RSi[0] + LQ0i * RSr[0];
        re[1] = LQ1r * RSr[1] - LQ1i * RSi[1]; im[1] = LQ1r * RSi[1] + LQ1i * RSr[1];
        re[2] = LQ0r * RSr[2] - LQ0i * RSi[2]; im[2] = LQ0r * RSi[2] + LQ0i * RSr[2];
        re[3] = LQ1r * RSr[3] - LQ1i * RSi[3]; im[3] = LQ1r * RSi[3] + LQ1i * RSr[3];
    }

    // --- depth-1 Rot gates on lane-bit wires (wire w on lane bit 5-w) ---
    gate_direct<5>(re, im, l5, g1 + 0 * kGateF);     // wire0: xor32 (shfl)
    gate_direct<4>(re, im, l4, g1 + 1 * kGateF);     // wire1: xor16 (shfl)
    gate_direct<3>(re, im, l3, g1 + 2 * kGateF);     // wire2: xor8 (DPP row_ror:8)
    gate_direct<2>(re, im, l2, g1 + 3 * kGateF);     // wire3: xor4 (shfl)
    gate_direct<1>(re, im, l1, g1 + 4 * kGateF);     // wire4: xor2 (DPP)
    gate_direct<0>(re, im, l0, g1 + 5 * kGateF);     // wire5: xor1 (DPP)

    // --- reg-bit wires via Hermitian forms; streams:
    //  P  = amp^dag amp            (gate-invariant)
    //  R1 = amp^dag (h6 x I) amp   (pairs (0,2),(1,3))
    //  R0 = amp^dag (I x h7) amp   (pairs (0,1),(2,3))
    const float p0 = re[0] * re[0] + im[0] * im[0];
    const float p1 = re[1] * re[1] + im[1] * im[1];
    const float p2 = re[2] * re[2] + im[2] * im[2];
    const float p3 = re[3] * re[3] + im[3] * im[3];
    float P = (p0 + p1) + (p2 + p3);
    const float* h6 = g1 + 6 * kGateF;
    const float* h7 = g1 + 7 * kGateF;
    const float z1r = re[0] * re[2] + im[0] * im[2] + re[1] * re[3] + im[1] * im[3];
    const float z1i = re[0] * im[2] - im[0] * re[2] + re[1] * im[3] - im[1] * re[3];
    float R1 = h6[0] * ((p0 + p1) - (p2 + p3)) + 2.0f * (h6[1] * z1r - h6[2] * z1i);
    const float z0r = re[0] * re[1] + im[0] * im[1] + re[2] * re[3] + im[2] * im[3];
    const float z0i = re[0] * im[1] - im[0] * re[1] + re[2] * im[3] - im[2] * re[3];
    float R0 = h7[0] * ((p0 - p1) + (p2 - p3)) + 2.0f * (h7[1] * z0r - h7[2] * z0i);

    // --- ring2 folded into Walsh parities: full WHT butterfly, W[m] at lane m ---
#pragma unroll
    for (int st = 0; st < 3; ++st) {
        float v = (st == 0) ? P : (st == 1) ? R1 : R0;
        float d;
        d = f_dpp<kDppXor1>(v);   v = d + signflip(v, sg[0]);
        d = f_dpp<kDppXor2>(v);   v = d + signflip(v, sg[1]);
        d = __shfl_xor(v, 4, 64); v = d + signflip(v, sg[2]);
        d = f_dpp<kDppXor8>(v);   v = d + signflip(v, sg[3]);
        d = __shfl_xor(v, 16, 64); v = d + signflip(v, sg[4]);
        d = __shfl_xor(v, 32, 64); v = d + signflip(v, sg[5]);
        if (st == 0) P = v; else if (st == 1) R1 = v; else R0 = v;
    }
    WPo = P; WR1o = R1; WR0o = R0;
}

// scatter the 8 expvals (E_w = Walsh coeffs at fixed lanes) to e[0..7]
// masks: E0:R1@10  E1:R0@5  E2:P@40  E3:P@20  E4:P@42  E5:P@21  E6:R1@42  E7:R0@21
template <typename PT>
__device__ __forceinline__ void scatter_ev(PT e, int lane, float P, float R1, float R0) {
    if (lane == 10) e[0] = R1;
    if (lane ==  5) e[1] = R0;
    if (lane == 40) e[2] = P;
    if (lane == 20) e[3] = P;
    if (lane == 42) { e[4] = P; e[6] = R1; }
    if (lane == 21) { e[5] = P; e[7] = R0; }
}

// ---------------- fused both-layer kernel ----------------
// block = 512 threads = 8 waves = the 8 circuits of one (t, sample);
// 1 sample per wave; layer-0 results exchanged through 256 B of LDS.
__global__ __launch_bounds__(512, 8) void fused_kernel(const float* __restrict__ x,
                                                       const float* __restrict__ gt,
                                                       float* __restrict__ out) {
    const int widx = __builtin_amdgcn_readfirstlane(threadIdx.x >> 6);  // circuit u
    const int lane = threadIdx.x & 63;
    const int tt = blockIdx.x >> 8;          // timestep
    const int b  = blockIdx.x & 255;         // sample

    __shared__ float exch[8][8];             // [block i][wire w]

    unsigned sg[6];
#pragma unroll
    for (int q = 0; q < 6; ++q) sg[q] = ((lane >> q) & 1u) << 31;

    const int c = tt * kNB + widx;
    float WP, WR1, WR0;
    float ang[8];

    // ---- phase 0: layer-0 circuit (t, widx), sample b ----
    {
        const float* g0 = gt + (size_t)c * kGates * kGateF;
        const float* g1 = g0 + 8 * kGateF;
        const float* ab = x + ((b * kT + tt) * kD + widx * kNQ);
#pragma unroll
        for (int w = 0; w < 8; ++w) ang[w] = ab[w];
        sim1(ang, g0, g1, lane, sg, WP, WR1, WR0);
        scatter_ev(&exch[widx][0], lane, WP, WR1, WR0);
    }
    __syncthreads();
    // ---- phase 1: layer-1 circuit (t, widx) gathers feature widx of every block ----
    {
        const float* g0 = gt + (size_t)(kCirc + c) * kGates * kGateF;
        const float* g1 = g0 + 8 * kGateF;
#pragma unroll
        for (int i = 0; i < 8; ++i) ang[i] = exch[i][widx];
        sim1(ang, g0, g1, lane, sg, WP, WR1, WR0);
        scatter_ev(out + ((b * kT + tt) * kD + widx * kNQ), lane, WP, WR1, WR0);
    }
}

}  // namespace

extern "C" void kernel_launch(void* const* d_in, const int* in_sizes, int n_in,
                              void* d_out, int out_size, void* d_ws, size_t ws_size,
                              hipStream_t stream) {
    const float* x     = (const float*)d_in[0];   // (B, T, D) fp32
    const float* theta = (const float*)d_in[1];   // (T, NL, NB, DEPTH, NQ, 3) fp32
    float* out = (float*)d_out;                   // (B, T, D) fp32

    float* gt = (float*)d_ws;                     // gate table: 2*64*16*8 floats (64 KB)

    precompute_gates<<<(kNL * kCirc * kGates + 255) / 256, 256, 0, stream>>>(theta, gt);
    // 8 timesteps x 256 samples; 512 threads = 8 circuits x 1 sample/wave
    fused_kernel<<<kT * kB, 512, 0, stream>>>(x, gt, out);
}

// Round 9
// 35.424 us; speedup vs baseline: 1.1675x; 1.1675x over previous
//
#include <hip/hip_runtime.h>

namespace {

typedef float v2f __attribute__((ext_vector_type(2)));

constexpr int kT   = 8;    // timesteps
constexpr int kB   = 256;  // batch
constexpr int kNQ  = 8;    // qubits per circuit
constexpr int kNB  = 8;    // blocks
constexpr int kD   = 64;   // features
constexpr int kNL  = 2;    // quantum layers
constexpr int kCirc = kT * kNB;        // 64 circuits per layer
constexpr int kGates = 2 * kNQ;        // 16 gate slots per circuit
constexpr int kGateF = 8;

// ---------------- Rot-gate precompute ----------------
// slots (d=0,w=0..7) and (d=1,w=0..5): full 2x2 complex gate (8 floats)
// slots (d=1,w=6..7): Hermitian h = g^dag Z g stored as (a, Re b, Im b, 0...)
__global__ void precompute_gates(const float* __restrict__ theta, float* __restrict__ gt) {
    int i = blockIdx.x * blockDim.x + threadIdx.x;
    if (i >= kNL * kCirc * kGates) return;
    int g = i & 15;
    int c = (i >> 4) & 63;
    int l = i >> 10;
    int t = c >> 3, u = c & 7;
    int d = g >> 3, w = g & 7;
    const float* th = theta + ((((t * kNL + l) * kNB + u) * 2 + d) * kNQ + w) * 3;
    float phi = th[0], tht = th[1], omg = th[2];
    float st, ct, sp, cp, sm, cm;
    __sincosf(0.5f * tht, &st, &ct);
    __sincosf(0.5f * (phi + omg), &sp, &cp);
    __sincosf(0.5f * (phi - omg), &sm, &cm);
    const float u00r =  ct * cp, u00i = -ct * sp;
    const float u01r = -st * cm, u01i = -st * sm;
    const float u10r =  st * cm, u10i = -st * sm;
    const float u11r =  ct * cp, u11i =  ct * sp;
    float* o = gt + i * kGateF;
    if (d == 1 && w >= 6) {
        // h = g^dag Z g: h00 = |u00|^2-|u10|^2, h01 = conj(u00)u01 - conj(u10)u11
        o[0] = (u00r * u00r + u00i * u00i) - (u10r * u10r + u10i * u10i);
        o[1] = (u00r * u01r + u00i * u01i) - (u10r * u11r + u10i * u11i);
        o[2] = (u00r * u01i - u00i * u01r) - (u10r * u11i - u10i * u11r);
        o[3] = 0.0f; o[4] = 0.0f; o[5] = 0.0f; o[6] = 0.0f; o[7] = 0.0f;
    } else {
        o[0] = u00r;  o[1] = u00i;
        o[2] = u01r;  o[3] = u01i;
        o[4] = u10r;  o[5] = u10i;
        o[6] = u11r;  o[7] = u11i;
    }
}

// ---------------- shuffle backends ----------------
template <int CTRL>
__device__ __forceinline__ float f_dpp(float x) {
    return __builtin_bit_cast(float, __builtin_amdgcn_update_dpp(
        0, __builtin_bit_cast(int, x), CTRL, 0xF, 0xF, true));
}
constexpr int kDppXor1 = 0xB1;   // quad_perm [1,0,3,2]  = lane^1
constexpr int kDppXor2 = 0x4E;   // quad_perm [2,3,0,1]  = lane^2
constexpr int kDppXor8 = 0x128;  // row_ror:8 (16-lane row) = lane^8  [validated r7/r8]

// partner fetch at lane distance 1<<MODE: 0,1,3 via DPP (VALU); 2,4,5 via shfl (DS)
template <int MODE>
__device__ __forceinline__ float lane_partner(float x) {
    if constexpr (MODE == 0) return f_dpp<kDppXor1>(x);
    else if constexpr (MODE == 1) return f_dpp<kDppXor2>(x);
    else if constexpr (MODE == 3) return f_dpp<kDppXor8>(x);
    else if constexpr (MODE == 2) return __shfl_xor(x, 4, 64);
    else if constexpr (MODE == 4) return __shfl_xor(x, 16, 64);
    else return __shfl_xor(x, 32, 64);
}
template <int MODE>
__device__ __forceinline__ v2f partner2(v2f v) {
    v2f r;
    r.x = lane_partner<MODE>(v.x);
    r.y = lane_partner<MODE>(v.y);
    return r;
}

__device__ __forceinline__ v2f sel2(int c, v2f a, v2f b) { return c ? a : b; }

// ---------------- gate helper (2 packed samples, 4 amps/lane) ----------------
// amp index k = (lane<<2)|reg; wire w -> index bit 7-w.
// wires 0..5 -> lane bits 5..0; wires 6,7 -> reg bits 1,0 (folded as Hermitian forms).
template <int MODE>
__device__ __forceinline__ void gate_p(v2f (&re)[4], v2f (&im)[4], int bit,
                                       const float* __restrict__ gp) {
    const float aR = bit ? gp[6] : gp[0];
    const float aI = bit ? gp[7] : gp[1];
    const float bR = bit ? gp[4] : gp[2];
    const float bI = bit ? gp[5] : gp[3];
#pragma unroll
    for (int r = 0; r < 4; ++r) {
        const v2f pre = partner2<MODE>(re[r]);
        const v2f pim = partner2<MODE>(im[r]);
        const v2f mre = re[r], mim = im[r];
        re[r] = aR * mre - aI * mim + bR * pre - bI * pim;   // v_pk_fma_f32 chain
        im[r] = aR * mim + aI * mre + bR * pim + bI * pre;
    }
}

// ---------------- one circuit sim: 2 packed samples, 3 Walsh streams out ----------------
// State after AngleEmbedding + depth-0 Rot + CNOT-ring1 built directly as a permuted
// spinor product; depth-1 Rot gates on lane-bit wires; reg-bit wires (6,7) folded as
// Hermitian quadratic forms; CNOT-ring2 folded into Walsh parities of the reduction.
__device__ __forceinline__ void sim2p(const float (&ang)[2][8],
                                      const float* __restrict__ g0,
                                      const float* __restrict__ g1,
                                      int lane, const v2f (&sv)[6],
                                      v2f& WPo, v2f& WR1o, v2f& WR0o) {
    const int l0 = lane & 1,        l1 = (lane >> 1) & 1, l2 = (lane >> 2) & 1;
    const int l3 = (lane >> 3) & 1, l4 = (lane >> 4) & 1, l5 = (lane >> 5) & 1;

    v2f re[4], im[4];
    {
        // per-wire spinor after RY(ang) then d0 Rot, packed over samples
        v2f spr[8][2], spi[8][2];
#pragma unroll
        for (int w = 0; w < 8; ++w) {
            float s0, c0, s1, c1;
            __sincosf(0.5f * ang[0][w], &s0, &c0);
            __sincosf(0.5f * ang[1][w], &s1, &c1);
            const v2f cs = {c0, c1}, sn = {s0, s1};
            const float* gp = g0 + w * kGateF;
            spr[w][0] = gp[0] * cs + gp[2] * sn;
            spi[w][0] = gp[1] * cs + gp[3] * sn;
            spr[w][1] = gp[4] * cs + gp[6] * sn;
            spi[w][1] = gp[5] * cs + gp[7] * sn;
        }
        // ring1 inverse bit map (x = pre-ring1 wire bits; (lane,reg) = post-ring1):
        //  x0=l5^r0  x1=l5^l4^r0  x2=l4^l3  x3=l3^l2  x4=l2^l1  x5=l1^l0
        //  x6=l0^r1  x7=r1^r0
        const int x2 = l4 ^ l3, x3 = l3 ^ l2, x4 = l2 ^ l1, x5 = l1 ^ l0;
        v2f t1r, t1i, t2r, t2i;
        {
            const v2f ar = sel2(x2, spr[2][1], spr[2][0]), ai = sel2(x2, spi[2][1], spi[2][0]);
            const v2f br = sel2(x3, spr[3][1], spr[3][0]), bi = sel2(x3, spi[3][1], spi[3][0]);
            t1r = ar * br - ai * bi; t1i = ar * bi + ai * br;
        }
        {
            const v2f ar = sel2(x4, spr[4][1], spr[4][0]), ai = sel2(x4, spi[4][1], spi[4][0]);
            const v2f br = sel2(x5, spr[5][1], spr[5][0]), bi = sel2(x5, spi[5][1], spi[5][0]);
            t2r = ar * br - ai * bi; t2i = ar * bi + ai * br;
        }
        const v2f Lr = t1r * t2r - t1i * t2i, Li = t1r * t2i + t1i * t2r;
        // Q(r0) = s0[l5^r0] * s1[l5^l4^r0]
        const int xa = l5, xb = l5 ^ l4;
        const v2f a0r = sel2(xa, spr[0][1], spr[0][0]), a0i = sel2(xa, spi[0][1], spi[0][0]);
        const v2f a1r = sel2(xa, spr[0][0], spr[0][1]), a1i = sel2(xa, spi[0][0], spi[0][1]);
        const v2f b0r = sel2(xb, spr[1][1], spr[1][0]), b0i = sel2(xb, spi[1][1], spi[1][0]);
        const v2f b1r = sel2(xb, spr[1][0], spr[1][1]), b1i = sel2(xb, spi[1][0], spi[1][1]);
        const v2f Q0r = a0r * b0r - a0i * b0i, Q0i = a0r * b0i + a0i * b0r;
        const v2f Q1r = a1r * b1r - a1i * b1i, Q1i = a1r * b1i + a1i * b1r;
        // R(r1) = s6[l0^r1]; S(r0,r1) = s7[r1^r0]
        const v2f R0r = sel2(l0, spr[6][1], spr[6][0]), R0i = sel2(l0, spi[6][1], spi[6][0]);
        const v2f R1r = sel2(l0, spr[6][0], spr[6][1]), R1i = sel2(l0, spi[6][0], spi[6][1]);
        const v2f S0r = spr[7][0], S0i = spi[7][0];
        const v2f S1r = spr[7][1], S1i = spi[7][1];
        v2f RSr[4], RSi[4];
        RSr[0] = R0r * S0r - R0i * S0i; RSi[0] = R0r * S0i + R0i * S0r;  // r=0
        RSr[1] = R0r * S1r - R0i * S1i; RSi[1] = R0r * S1i + R0i * S1r;  // r=1
        RSr[2] = R1r * S1r - R1i * S1i; RSi[2] = R1r * S1i + R1i * S1r;  // r=2
        RSr[3] = R1r * S0r - R1i * S0i; RSi[3] = R1r * S0i + R1i * S0r;  // r=3
        const v2f LQ0r = Lr * Q0r - Li * Q0i, LQ0i = Lr * Q0i + Li * Q0r;
        const v2f LQ1r = Lr * Q1r - Li * Q1i, LQ1i = Lr * Q1i + Li * Q1r;
        re[0] = LQ0r * RSr[0] - LQ0i * RSi[0]; im[0] = LQ0r * RSi[0] + LQ0i * RSr[0];
        re[1] = LQ1r * RSr[1] - LQ1i * RSi[1]; im[1] = LQ1r * RSi[1] + LQ1i * RSr[1];
        re[2] = LQ0r * RSr[2] - LQ0i * RSi[2]; im[2] = LQ0r * RSi[2] + LQ0i * RSr[2];
        re[3] = LQ1r * RSr[3] - LQ1i * RSi[3]; im[3] = LQ1r * RSi[3] + LQ1i * RSr[3];
    }

    // --- depth-1 Rot gates on lane-bit wires (wire w on lane bit 5-w) ---
    gate_p<5>(re, im, l5, g1 + 0 * kGateF);     // wire0: xor32 (shfl)
    gate_p<4>(re, im, l4, g1 + 1 * kGateF);     // wire1: xor16 (shfl)
    gate_p<3>(re, im, l3, g1 + 2 * kGateF);     // wire2: xor8 (DPP row_ror:8)
    gate_p<2>(re, im, l2, g1 + 3 * kGateF);     // wire3: xor4 (shfl)
    gate_p<1>(re, im, l1, g1 + 4 * kGateF);     // wire4: xor2 (DPP)
    gate_p<0>(re, im, l0, g1 + 5 * kGateF);     // wire5: xor1 (DPP)

    // --- reg-bit wires via Hermitian forms (packed) ---
    const v2f p0 = re[0] * re[0] + im[0] * im[0];
    const v2f p1 = re[1] * re[1] + im[1] * im[1];
    const v2f p2 = re[2] * re[2] + im[2] * im[2];
    const v2f p3 = re[3] * re[3] + im[3] * im[3];
    v2f P = (p0 + p1) + (p2 + p3);
    const float* h6 = g1 + 6 * kGateF;
    const float* h7 = g1 + 7 * kGateF;
    const v2f z1r = re[0] * re[2] + im[0] * im[2] + re[1] * re[3] + im[1] * im[3];
    const v2f z1i = re[0] * im[2] - im[0] * re[2] + re[1] * im[3] - im[1] * re[3];
    v2f R1 = h6[0] * ((p0 + p1) - (p2 + p3)) + 2.0f * (h6[1] * z1r - h6[2] * z1i);
    const v2f z0r = re[0] * re[1] + im[0] * im[1] + re[2] * re[3] + im[2] * im[3];
    const v2f z0i = re[0] * im[1] - im[0] * re[1] + re[2] * im[3] - im[2] * re[3];
    v2f R0 = h7[0] * ((p0 - p1) + (p2 - p3)) + 2.0f * (h7[1] * z0r - h7[2] * z0i);

    // --- ring2 folded into Walsh parities: full WHT butterfly, W[m] at lane m ---
    // per level: v' = partner + sv[q] * v  (sv = packed ±1 from lane bit q)
#pragma unroll
    for (int st = 0; st < 3; ++st) {
        v2f v = (st == 0) ? P : (st == 1) ? R1 : R0;
        v2f d;
        d = partner2<0>(v); v = d + sv[0] * v;
        d = partner2<1>(v); v = d + sv[1] * v;
        d = partner2<2>(v); v = d + sv[2] * v;
        d = partner2<3>(v); v = d + sv[3] * v;
        d = partner2<4>(v); v = d + sv[4] * v;
        d = partner2<5>(v); v = d + sv[5] * v;
        if (st == 0) P = v; else if (st == 1) R1 = v; else R0 = v;
    }
    WPo = P; WR1o = R1; WR0o = R0;
}

// scatter the 8 expvals (E_w = Walsh coeffs at fixed lanes) to e[0..7]
// masks: E0:R1@10  E1:R0@5  E2:P@40  E3:P@20  E4:P@42  E5:P@21  E6:R1@42  E7:R0@21
template <typename PT>
__device__ __forceinline__ void scatter_ev(PT e, int lane, float P, float R1, float R0) {
    if (lane == 10) e[0] = R1;
    if (lane ==  5) e[1] = R0;
    if (lane == 40) e[2] = P;
    if (lane == 20) e[3] = P;
    if (lane == 42) { e[4] = P; e[6] = R1; }
    if (lane == 21) { e[5] = P; e[7] = R0; }
}

// ---------------- fused both-layer kernel ----------------
// block = 512 threads = 8 waves = the 8 circuits of one (t, sample-pair);
// 2 packed samples per wave; layer-0 results exchanged through 512 B of LDS.
__global__ __launch_bounds__(512, 4) void fused_kernel(const float* __restrict__ x,
                                                       const float* __restrict__ gt,
                                                       float* __restrict__ out) {
    const int widx = __builtin_amdgcn_readfirstlane(threadIdx.x >> 6);  // circuit u
    const int lane = threadIdx.x & 63;
    const int tt = blockIdx.x >> 7;          // timestep
    const int b0 = (blockIdx.x & 127) << 1;  // first sample of pair

    __shared__ float exch[2][8][8];          // [sample][block i][wire w]

    v2f sv[6];
#pragma unroll
    for (int q = 0; q < 6; ++q) {
        const float s = ((lane >> q) & 1) ? -1.0f : 1.0f;
        sv[q].x = s; sv[q].y = s;
    }

    const int c = tt * kNB + widx;
    v2f WP, WR1, WR0;
    float ang[2][8];

    // ---- phase 0: layer-0 circuit (t, widx), samples b0, b0+1 ----
    {
        const float* g0 = gt + (size_t)c * kGates * kGateF;
        const float* g1 = g0 + 8 * kGateF;
#pragma unroll
        for (int s = 0; s < 2; ++s) {
            const float* ab = x + (((b0 + s) * kT + tt) * kD + widx * kNQ);
#pragma unroll
            for (int w = 0; w < 8; ++w) ang[s][w] = ab[w];
        }
        sim2p(ang, g0, g1, lane, sv, WP, WR1, WR0);
        scatter_ev(&exch[0][widx][0], lane, WP.x, WR1.x, WR0.x);
        scatter_ev(&exch[1][widx][0], lane, WP.y, WR1.y, WR0.y);
    }
    __syncthreads();
    // ---- phase 1: layer-1 circuit (t, widx) gathers feature widx of every block ----
    {
        const float* g0 = gt + (size_t)(kCirc + c) * kGates * kGateF;
        const float* g1 = g0 + 8 * kGateF;
#pragma unroll
        for (int s = 0; s < 2; ++s)
#pragma unroll
            for (int i = 0; i < 8; ++i) ang[s][i] = exch[s][i][widx];
        sim2p(ang, g0, g1, lane, sv, WP, WR1, WR0);
        scatter_ev(out + (((b0 + 0) * kT + tt) * kD + widx * kNQ), lane, WP.x, WR1.x, WR0.x);
        scatter_ev(out + (((b0 + 1) * kT + tt) * kD + widx * kNQ), lane, WP.y, WR1.y, WR0.y);
    }
}

}  // namespace

extern "C" void kernel_launch(void* const* d_in, const int* in_sizes, int n_in,
                              void* d_out, int out_size, void* d_ws, size_t ws_size,
                              hipStream_t stream) {
    const float* x     = (const float*)d_in[0];   // (B, T, D) fp32
    const float* theta = (const float*)d_in[1];   // (T, NL, NB, DEPTH, NQ, 3) fp32
    float* out = (float*)d_out;                   // (B, T, D) fp32

    float* gt = (float*)d_ws;                     // gate table: 2*64*16*8 floats (64 KB)

    precompute_gates<<<(kNL * kCirc * kGates + 255) / 256, 256, 0, stream>>>(theta, gt);
    // 8 timesteps x 128 sample-pairs; 512 threads = 8 circuits x 2 packed samples/wave
    fused_kernel<<<kT * (kB / 2), 512, 0, stream>>>(x, gt, out);
}